// Round 11
// baseline (91.963 us; speedup 1.0000x reference)
//
#include <hip/hip_runtime.h>
#include <hip/hip_bf16.h>
#include <stdint.h>

// Problem constants
#define NB    32    // batch
#define CIN   128
#define HH    56
#define WW    56
#define COUT  256
#define HP    58    // padded height (H+2)
#define WP    64    // padded width (56+2 -> padded to 64)

// ws layout: xp (bf16, NB*HP*WP*CIN) then wpack (bf16, 9*4*4*256*8)
#define XP_ELEMS   (NB * HP * WP * CIN)

typedef __attribute__((ext_vector_type(4))) float f32x4;
typedef __attribute__((ext_vector_type(8))) short bf16x8;

__device__ __forceinline__ unsigned short f2bf(float f) {
    union { float f; unsigned u; } v; v.f = f;
    unsigned r = v.u + 0x7FFFu + ((v.u >> 16) & 1u);
    return (unsigned short)(r >> 16);
}

__device__ __forceinline__ void gload16(const void* g, void* l) {
    __builtin_amdgcn_global_load_lds(
        (__attribute__((address_space(1))) void*)(void*)g,
        (__attribute__((address_space(3))) void*)l,
        16, 0, 0);
}

// ---------------------------------------------------------------------------
// Fused prep: blocks [0,256) compose weights; blocks [256,256+HP*NB) pack x.
// ---------------------------------------------------------------------------
__global__ __launch_bounds__(256) void prep(
    const float* __restrict__ x, const float* __restrict__ dict,
    const float* __restrict__ coef, const int* __restrict__ idxw,
    unsigned short* __restrict__ wpack, unsigned short* __restrict__ xp) {
    int tid = threadIdx.x;

    if (blockIdx.x < COUT) {
        // ---- build_weight: wpack[pos][cib][kpos][o][kin] ----
        int o = blockIdx.x;
        bool mode64 = (idxw[1] == 0) && (idxw[3] == 0) && (idxw[5] == 0) &&
                      (idxw[7] == 0) && (idxw[9] == 0) && (idxw[11] == 0) &&
                      (idxw[13] == 0) && (idxw[15] == 0);
        float c[8]; int di[8];
#pragma unroll
        for (int s = 0; s < 8; ++s) {
            c[s]  = coef[o * 8 + s];
            di[s] = mode64 ? idxw[(o * 8 + s) * 2] : idxw[o * 8 + s];
        }
        for (int j = tid; j < 9 * 128; j += 256) {
            int pos = j >> 7;          // 0..8
            int ci  = j & 127;
            int kh = pos / 3, kw = pos - kh * 3;
            float v = 0.f;
#pragma unroll
            for (int s = 0; s < 8; ++s)
                v += c[s] * dict[((di[s] * CIN + ci) * 3 + kh) * 3 + kw];
            int cib = ci >> 5, kpos = (ci >> 3) & 3, kin = ci & 7;
            wpack[((((pos * 4 + cib) * 4 + kpos) * COUT + o) << 3) + kin] = f2bf(v);
        }
        return;
    }

    // ---- pack_x: NCHW fp32 -> zero-padded NHWC bf16 ----
    int idx = blockIdx.x - COUT;
    int ih = idx % HP;         // 0..57
    int b  = idx / HP;         // 0..31
    size_t obase = ((size_t)(b * HP + ih)) * WP * CIN;
    bf16x8* outv = (bf16x8*)(xp + obase);   // 1024 vectors of 8 bf16

    if (ih == 0 || ih == HP - 1) {
        bf16x8 z = {0, 0, 0, 0, 0, 0, 0, 0};
        for (int e = tid; e < WP * CIN / 8; e += 256) outv[e] = z;
        return;
    }

    __shared__ float xs[CIN][WW + 1];   // +1 pad: odd stride
    int h = ih - 1;
    for (int e = tid; e < CIN * WW; e += 256) {
        int ci = e / WW, w = e - ci * WW;
        xs[ci][w] = x[(((size_t)b * CIN + ci) * HH + h) * WW + w];
    }
    __syncthreads();
    for (int ch = tid; ch < WP * CIN / 8; ch += 256) {
        int iw = ch >> 4;            // 0..63
        int cb = (ch & 15) << 3;     // ci base, 0..120
        bf16x8 v = {0, 0, 0, 0, 0, 0, 0, 0};
        if (iw >= 1 && iw <= WW) {
#pragma unroll
            for (int j = 0; j < 8; ++j)
                v[j] = (short)f2bf(xs[cb + j][iw - 1]);
        }
        outv[ch] = v;
    }
}

// ---------------------------------------------------------------------------
// Main: implicit-GEMM conv.
// R11 (R10 post-mortem: A-fragment L2 traffic was ~92% of the per-CU L2
// ceiling at MFMA-bound rate; scheduling tweaks were null because BW was
// the wall). Double the MFMA work per A-byte:
//  - Block = 256 threads = 4 waves = 256 Cout x TWO output rows.
//    Wave = 64 Cout x 2 rows x 64 cols; acc[4][2][4] = 128 AGPR.
//    A demand at MFMA-bound rate drops 52 -> 26 B/cyc/CU.
//  - (256,2): 256 unified regs/wave (acc 128 + af ping-pong 32 + bfr 32
//    + addr ~= 230, no spill). 2 blocks/CU, 2 waves/SIMD.
//  - A: direct global->reg, PING-PONG sets af[(cib+pos)&1] (no v_mov
//    rotation); index static under #pragma unroll 2 on cib (rule #20).
//  - B: 4-row tile [rr(4)][kpos(4)][iw(64)][kin(8)] = 16.6 KB incl pad,
//    double-buffered, staged once per cib; counted s_waitcnt vmcnt(4)
//    (the 4 in-flight af loads ride across) + s_barrier, 3x per block.
//  - B fragments read just-in-time at cluster top: ~120 cyc LDS latency
//    under the 620-cyc MFMA cluster, covered by the other wave.
// ---------------------------------------------------------------------------
__global__ __launch_bounds__(256, 2) void conv_mfma(
    const unsigned short* __restrict__ xp,
    const unsigned short* __restrict__ wpack,
    float* __restrict__ out) {
    // B tile: chunk (rr*4+kpos)*64+iw holds 8 bf16; +128 elem pad (kw spill)
    __shared__ unsigned short Bl[2][4 * 4 * 64 * 8 + 128];

    int tid  = threadIdx.x;
    int lane = tid & 63;
    int wid  = tid >> 6;       // 0..3 = Cout slice of 64

    // XCD-bijective swizzle: 896 = 8 * 112; each XCD gets 4 consecutive b's
    int flat = blockIdx.x;
    int swz  = (flat & 7) * 112 + (flat >> 3);
    int b    = swz / 28;       // 0..31
    int oh0  = (swz % 28) * 2; // output rows oh0, oh0+1

    const int klane = lane >> 4;   // k-group (0..3)
    const int fl    = lane & 15;

    f32x4 acc[4][2][4];
    f32x4 zero = {0.f, 0.f, 0.f, 0.f};
#pragma unroll
    for (int i = 0; i < 4; ++i)
#pragma unroll
        for (int j = 0; j < 2; ++j)
#pragma unroll
            for (int k = 0; k < 4; ++k) acc[i][j][k] = zero;

    // Per-lane A-fragment base: af(tile,mf) at ap + tile*8192 + mf*128 (elems)
    const unsigned short* ap0 = wpack + ((size_t)klane * 256 + wid * 64 + fl) * 8;

    // B staging: thread stages rows k=0..3 at kpos=wid, iw=lane
    const unsigned short* bs =
        xp + (((size_t)(b * HP + oh0)) * WP + lane) * CIN + wid * 8;

    // ---- prologue: stage B(cib0); preload af set 0 for tap (0,0) ----
#pragma unroll
    for (int k = 0; k < 4; ++k)
        gload16(bs + (size_t)k * 8192, &Bl[0][(k * 4 + wid) * 512]);

    bf16x8 af[2][4];
#pragma unroll
    for (int mf = 0; mf < 4; ++mf)
        af[0][mf] = *(const bf16x8*)(ap0 + mf * 128);
    asm volatile("s_waitcnt vmcnt(4)" ::: "memory");   // B(0) in; af flying
    __builtin_amdgcn_s_barrier();

    const unsigned short* apc = ap0;   // += 8192 elems per cib

#pragma unroll 2
    for (int cib = 0; cib < 4; ++cib) {
        const int bbuf = cib & 1;

        // ---- stage B(cib+1) into other buffer: 9 taps of slack ----
        if (cib < 3) {
#pragma unroll
            for (int k = 0; k < 4; ++k)
                gload16(bs + (cib + 1) * 32 + (size_t)k * 8192,
                        &Bl[bbuf ^ 1][(k * 4 + wid) * 512]);
        }

#pragma unroll
        for (int pos = 0; pos < 9; ++pos) {
            const int kh = pos / 3, kw = pos - kh * 3;
            const int cur = (cib + pos) & 1;   // static under unroll-2 cib

            // ---- A prefetch for next tap into the free set (ping-pong) ----
            if (pos < 8) {
#pragma unroll
                for (int mf = 0; mf < 4; ++mf)
                    af[cur ^ 1][mf] =
                        *(const bf16x8*)(apc + (pos + 1) * 32768 + mf * 128);
            } else if (cib < 3) {
#pragma unroll
                for (int mf = 0; mf < 4; ++mf)
                    af[cur ^ 1][mf] = *(const bf16x8*)(apc + 8192 + mf * 128);
            }

            // ---- B fragments just-in-time (both rows) ----
            bf16x8 bfr[2][4];
#pragma unroll
            for (int r = 0; r < 2; ++r) {
                const int rr = r + kh;
#pragma unroll
                for (int nf = 0; nf < 4; ++nf) {
                    int ch = (rr * 4 + klane) * 64 + nf * 16 + fl + kw;
                    bfr[r][nf] = *(const bf16x8*)&Bl[bbuf][ch * 8];
                }
            }

            // ---- 32 MFMA on af[cur] (loaded a full tap ago) ----
            __builtin_amdgcn_s_setprio(1);
#pragma unroll
            for (int r = 0; r < 2; ++r)
#pragma unroll
                for (int mf = 0; mf < 4; ++mf)
#pragma unroll
                    for (int nf = 0; nf < 4; ++nf)
                        acc[mf][r][nf] = __builtin_amdgcn_mfma_f32_16x16x32_bf16(
                            af[cur][mf], bfr[r][nf], acc[mf][r][nf], 0, 0, 0);
            __builtin_amdgcn_s_setprio(0);
        }

        apc += 8192;
        if (cib < 3) {
            // counted: B(cib+1) staged (in-order retire) while the 4 af
            // loads issued at pos8 stay in flight across the barrier
            asm volatile("s_waitcnt vmcnt(4) lgkmcnt(0)" ::: "memory");
            __builtin_amdgcn_s_barrier();
        }
    }

    // Epilogue: C/D layout col = lane&15, row = (lane>>4)*4 + reg (m89-verified)
#pragma unroll
    for (int r = 0; r < 2; ++r) {
        int oh = oh0 + r;
#pragma unroll
        for (int nf = 0; nf < 4; ++nf) {
            int ow = nf * 16 + fl;
            if (ow < WW) {
#pragma unroll
                for (int mf = 0; mf < 4; ++mf) {
                    int ob = wid * 64 + mf * 16 + (lane >> 4) * 4;
                    float* dst = out + (((size_t)b * COUT + ob) * HH + oh) * WW + ow;
#pragma unroll
                    for (int reg = 0; reg < 4; ++reg)
                        dst[(size_t)reg * HH * WW] = acc[mf][r][nf][reg];
                }
            }
        }
    }
}

extern "C" void kernel_launch(void* const* d_in, const int* in_sizes, int n_in,
                              void* d_out, int out_size, void* d_ws, size_t ws_size,
                              hipStream_t stream) {
    const float* x    = (const float*)d_in[0];
    const float* dict = (const float*)d_in[1];
    const float* coef = (const float*)d_in[2];
    const int*   idxw = (const int*)d_in[3];
    float* out = (float*)d_out;

    unsigned short* xp    = (unsigned short*)d_ws;
    unsigned short* wpack = xp + XP_ELEMS;

    prep<<<dim3(COUT + HP * NB), dim3(256), 0, stream>>>(x, dict, coef, idxw, wpack, xp);
    conv_mfma<<<dim3(28 * NB), dim3(256), 0, stream>>>(xp, wpack, out);
}

// Round 13
// 90.294 us; speedup vs baseline: 1.0185x; 1.0185x over previous
//
#include <hip/hip_runtime.h>
#include <hip/hip_bf16.h>
#include <stdint.h>

// Problem constants
#define NB    32    // batch
#define CIN   128
#define HH    56
#define WW    56
#define COUT  256
#define HP    58    // padded height (H+2)
#define WP    64    // padded width (56+2 -> padded to 64)

// ws layout: xp (bf16, NB*HP*WP*CIN) then wpack (bf16, 36*8192)
#define XP_ELEMS   (NB * HP * WP * CIN)

typedef __attribute__((ext_vector_type(4))) float f32x4;
typedef __attribute__((ext_vector_type(8))) short bf16x8;

__device__ __forceinline__ unsigned short f2bf(float f) {
    union { float f; unsigned u; } v; v.f = f;
    unsigned r = v.u + 0x7FFFu + ((v.u >> 16) & 1u);
    return (unsigned short)(r >> 16);
}

__device__ __forceinline__ void gload16(const void* g, void* l) {
    __builtin_amdgcn_global_load_lds(
        (__attribute__((address_space(1))) void*)(void*)g,
        (__attribute__((address_space(3))) void*)l,
        16, 0, 0);
}

// ---------------------------------------------------------------------------
// Fused prep: blocks [0,256) compose weights; blocks [256,256+HP*NB) pack x.
//
// wpack layout (R13, stride-fixed): [tile(36)][wid(4)][mf(4)][lane(64)][kin(8)]
// elem = tile*8192 + wid*2048 + mf*512 + lane*8 + kin, where tile = pos*4+cib,
// o = wid*64 + mf*16 + fl, lane = kpos*16 + fl, ci = cib*32 + kpos*8 + kin.
// Each A-fragment WAVE-LOAD is contiguous (lane l -> lane*16B): 8 cache
// lines per load instead of the 64-line gather of the [kpos][o][kin] layout.
// (R12 bug: mf stride was 1024 -> (wid,mf) blocks overlapped -> collisions.)
// ---------------------------------------------------------------------------
__global__ __launch_bounds__(256) void prep(
    const float* __restrict__ x, const float* __restrict__ dict,
    const float* __restrict__ coef, const int* __restrict__ idxw,
    unsigned short* __restrict__ wpack, unsigned short* __restrict__ xp) {
    int tid = threadIdx.x;

    if (blockIdx.x < COUT) {
        // ---- build_weight ----
        int o = blockIdx.x;
        bool mode64 = (idxw[1] == 0) && (idxw[3] == 0) && (idxw[5] == 0) &&
                      (idxw[7] == 0) && (idxw[9] == 0) && (idxw[11] == 0) &&
                      (idxw[13] == 0) && (idxw[15] == 0);
        float c[8]; int di[8];
#pragma unroll
        for (int s = 0; s < 8; ++s) {
            c[s]  = coef[o * 8 + s];
            di[s] = mode64 ? idxw[(o * 8 + s) * 2] : idxw[o * 8 + s];
        }
        const int wid = o >> 6, mf = (o >> 4) & 3, fl = o & 15;
        for (int j = tid; j < 9 * 128; j += 256) {
            int pos = j >> 7;          // 0..8
            int ci  = j & 127;
            int kh = pos / 3, kw = pos - kh * 3;
            float v = 0.f;
#pragma unroll
            for (int s = 0; s < 8; ++s)
                v += c[s] * dict[((di[s] * CIN + ci) * 3 + kh) * 3 + kw];
            int tile = pos * 4 + (ci >> 5);
            int kpos = (ci >> 3) & 3, kin = ci & 7;
            wpack[tile * 8192 + wid * 2048 + mf * 512 + (kpos * 16 + fl) * 8 + kin]
                = f2bf(v);
        }
        return;
    }

    // ---- pack_x: NCHW fp32 -> zero-padded NHWC bf16 ----
    int idx = blockIdx.x - COUT;
    int ih = idx % HP;         // 0..57
    int b  = idx / HP;         // 0..31
    size_t obase = ((size_t)(b * HP + ih)) * WP * CIN;
    bf16x8* outv = (bf16x8*)(xp + obase);   // 1024 vectors of 8 bf16

    if (ih == 0 || ih == HP - 1) {
        bf16x8 z = {0, 0, 0, 0, 0, 0, 0, 0};
        for (int e = tid; e < WP * CIN / 8; e += 256) outv[e] = z;
        return;
    }

    __shared__ float xs[CIN][WW + 1];   // +1 pad: odd stride
    int h = ih - 1;
    for (int e = tid; e < CIN * WW; e += 256) {
        int ci = e / WW, w = e - ci * WW;
        xs[ci][w] = x[(((size_t)b * CIN + ci) * HH + h) * WW + w];
    }
    __syncthreads();
    for (int ch = tid; ch < WP * CIN / 8; ch += 256) {
        int iw = ch >> 4;            // 0..63
        int cb = (ch & 15) << 3;     // ci base, 0..120
        bf16x8 v = {0, 0, 0, 0, 0, 0, 0, 0};
        if (iw >= 1 && iw <= WW) {
#pragma unroll
            for (int j = 0; j < 8; ++j)
                v[j] = (short)f2bf(xs[cb + j][iw - 1]);
        }
        outv[ch] = v;
    }
}

// ---------------------------------------------------------------------------
// Main: implicit-GEMM conv.  R13 = R9's exact structure (equal-best, 73us)
// with ONE change vs R9: wpack permuted so A-fragment wave-loads are
// contiguous (see prep comment; R12's version had the mf-stride bug).
//  - Block = 256 threads = 4 waves = 256 Cout x ONE output row; 3 blocks/CU
//    at (256,3) -> 12 waves/CU; acc[4][4] = 64 AGPR, ~84 arch VGPR.
//  - A: direct global->reg dist-1 (afc/afn rotation), now coalesced.
//  - B: 3-row LDS tile, double-buffered, 3 barriers/block, bfr JIT reads
//    (R10 showed bfn reg-pipelining is null).
// ---------------------------------------------------------------------------
__global__ __launch_bounds__(256, 3) void conv_mfma(
    const unsigned short* __restrict__ xp,
    const unsigned short* __restrict__ wpack,
    float* __restrict__ out) {
    // B tile: chunks (rr*4+kpos)*64+iw of 16B; 768 chunks + pad for kw spill
    __shared__ unsigned short Bl[2][3 * 4 * 64 * 8 + 128];

    int tid  = threadIdx.x;
    int lane = tid & 63;
    int wid  = tid >> 6;       // 0..3 = wm (Cout slice of 64)

    // XCD-bijective swizzle: 1792 = 8 * 224; each XCD gets 4 consecutive b's
    int flat = blockIdx.x;
    int swz  = (flat & 7) * 224 + (flat >> 3);
    int b    = swz / 56;       // 0..31
    int oh   = swz % 56;       // output row

    const int klane = lane >> 4;   // k-group (0..3)
    const int fl    = lane & 15;

    f32x4 acc[4][4];
    f32x4 zero = {0.f, 0.f, 0.f, 0.f};
#pragma unroll
    for (int i = 0; i < 4; ++i)
#pragma unroll
        for (int j = 0; j < 4; ++j) acc[i][j] = zero;

    // Per-lane A-fragment base (coalesced layout): af(tile,mf) at
    // ap0 + tile*8192 + mf*512 elems; lane stride 8 elems = 16 B.
    const unsigned short* ap0 = wpack + (size_t)wid * 2048 + lane * 8;

    // B staging: thread stages chunks (rr=k, kpos=wid, iw=lane), k=0..2
    const unsigned short* bs =
        xp + (((size_t)(b * HP + oh)) * WP + lane) * CIN + wid * 8;

    // ---- prologue: stage B(cib0); preload A(tile 0) ----
#pragma unroll
    for (int k = 0; k < 3; ++k)
        gload16(bs + (size_t)k * 8192, &Bl[0][(k * 256 + wid * 64) * 8]);

    bf16x8 afc[4], afn[4];
#pragma unroll
    for (int mf = 0; mf < 4; ++mf)
        afc[mf] = *(const bf16x8*)(ap0 + mf * 512);
    __syncthreads();

    const unsigned short* apc = ap0;   // += 8192 elems per cib

#pragma unroll 1
    for (int cib = 0; cib < 4; ++cib) {
        const int bbuf = cib & 1;

        // ---- stage B(cib+1) into other buffer: 9 taps of slack ----
        if (cib < 3) {
#pragma unroll
            for (int k = 0; k < 3; ++k)
                gload16(bs + (cib + 1) * 32 + (size_t)k * 8192,
                        &Bl[bbuf ^ 1][(k * 256 + wid * 64) * 8]);
        }

#pragma unroll
        for (int pos = 0; pos < 9; ++pos) {
            const int kh = pos / 3, kw = pos - kh * 3;

            // ---- prefetch A(next tap) into afn (dist-1 reg pipeline) ----
            if (pos < 8) {
#pragma unroll
                for (int mf = 0; mf < 4; ++mf)
                    afn[mf] = *(const bf16x8*)(apc + (pos + 1) * 32768 + mf * 512);
            } else if (cib < 3) {
#pragma unroll
                for (int mf = 0; mf < 4; ++mf)
                    afn[mf] = *(const bf16x8*)(apc + 8192 + mf * 512);
            }

            // ---- B fragments from LDS (JIT) ----
            bf16x8 bfr[4];
#pragma unroll
            for (int nf = 0; nf < 4; ++nf) {
                int ch = kh * 256 + klane * 64 + nf * 16 + fl + kw;  // junk -> pad
                bfr[nf] = *(const bf16x8*)&Bl[bbuf][ch * 8];
            }

            // ---- MFMA on afc (loaded a full tap ago) ----
            __builtin_amdgcn_s_setprio(1);
#pragma unroll
            for (int mf = 0; mf < 4; ++mf)
#pragma unroll
                for (int nf = 0; nf < 4; ++nf)
                    acc[mf][nf] = __builtin_amdgcn_mfma_f32_16x16x32_bf16(
                        afc[mf], bfr[nf], acc[mf][nf], 0, 0, 0);
            __builtin_amdgcn_s_setprio(0);

            // rotate the register pipeline
#pragma unroll
            for (int mf = 0; mf < 4; ++mf) afc[mf] = afn[mf];
        }

        apc += 8192;
        if (cib < 3) __syncthreads();   // next B resident (9 taps of flight)
    }

    // Epilogue: C/D layout col = lane&15, row = (lane>>4)*4 + reg (m89-verified)
#pragma unroll
    for (int nf = 0; nf < 4; ++nf) {
        int ow = nf * 16 + fl;
        if (ow < WW) {
#pragma unroll
            for (int mf = 0; mf < 4; ++mf) {
                int ob = wid * 64 + mf * 16 + (lane >> 4) * 4;
                float* dst = out + (((size_t)b * COUT + ob) * HH + oh) * WW + ow;
#pragma unroll
                for (int r = 0; r < 4; ++r)
                    dst[(size_t)r * HH * WW] = acc[mf][nf][r];
            }
        }
    }
}

extern "C" void kernel_launch(void* const* d_in, const int* in_sizes, int n_in,
                              void* d_out, int out_size, void* d_ws, size_t ws_size,
                              hipStream_t stream) {
    const float* x    = (const float*)d_in[0];
    const float* dict = (const float*)d_in[1];
    const float* coef = (const float*)d_in[2];
    const int*   idxw = (const int*)d_in[3];
    float* out = (float*)d_out;

    unsigned short* xp    = (unsigned short*)d_ws;
    unsigned short* wpack = xp + XP_ELEMS;

    prep<<<dim3(COUT + HP * NB), dim3(256), 0, stream>>>(x, dict, coef, idxw, wpack, xp);
    conv_mfma<<<dim3(NB * 56), dim3(256), 0, stream>>>(xp, wpack, out);
}

// Round 14
// 85.247 us; speedup vs baseline: 1.0788x; 1.0592x over previous
//
#include <hip/hip_runtime.h>
#include <hip/hip_bf16.h>
#include <stdint.h>

// Problem constants
#define NB    32    // batch
#define CIN   128
#define HH    56
#define WW    56
#define COUT  256
#define HP    58    // padded height (H+2)
#define WP    64    // padded width (56+2 -> padded to 64)

// ws layout: xp (bf16, NB*HP*WP*CIN) then wpack (bf16, 36*8192)
#define XP_ELEMS   (NB * HP * WP * CIN)

typedef __attribute__((ext_vector_type(4))) float f32x4;
typedef __attribute__((ext_vector_type(8))) short bf16x8;

__device__ __forceinline__ unsigned short f2bf(float f) {
    union { float f; unsigned u; } v; v.f = f;
    unsigned r = v.u + 0x7FFFu + ((v.u >> 16) & 1u);
    return (unsigned short)(r >> 16);
}

__device__ __forceinline__ void gload16(const void* g, void* l) {
    __builtin_amdgcn_global_load_lds(
        (__attribute__((address_space(1))) void*)(void*)g,
        (__attribute__((address_space(3))) void*)l,
        16, 0, 0);
}

// ---------------------------------------------------------------------------
// Fused prep: blocks [0,256) compose weights; blocks [256,256+HP*NB) pack x.
//
// wpack layout (R13-verified): [tile(36)][wid(4)][mf(4)][lane(64)][kin(8)]
//   elem = tile*8192 + wid*2048 + mf*512 + lane*8 + kin; tile = pos*4+cib,
//   o = wid*64+mf*16+fl, lane = kpos*16+fl, ci = cib*32+kpos*8+kin.
// xp layout (R14 NEW): [b][ih][ch(16)][iw(64)][kin(8)], ch = ci>>3.
//   Makes the conv's B-slab staging a LINEAR 1-KB-slice copy and the
//   B-fragment ds_reads pure imm-offset with the proven conflict-free
//   16B-stride pattern.
// ---------------------------------------------------------------------------
__global__ __launch_bounds__(256) void prep(
    const float* __restrict__ x, const float* __restrict__ dict,
    const float* __restrict__ coef, const int* __restrict__ idxw,
    unsigned short* __restrict__ wpack, unsigned short* __restrict__ xp) {
    int tid = threadIdx.x;

    if (blockIdx.x < COUT) {
        // ---- build_weight ----
        int o = blockIdx.x;
        bool mode64 = (idxw[1] == 0) && (idxw[3] == 0) && (idxw[5] == 0) &&
                      (idxw[7] == 0) && (idxw[9] == 0) && (idxw[11] == 0) &&
                      (idxw[13] == 0) && (idxw[15] == 0);
        float c[8]; int di[8];
#pragma unroll
        for (int s = 0; s < 8; ++s) {
            c[s]  = coef[o * 8 + s];
            di[s] = mode64 ? idxw[(o * 8 + s) * 2] : idxw[o * 8 + s];
        }
        const int wid = o >> 6, mf = (o >> 4) & 3, fl = o & 15;
        for (int j = tid; j < 9 * 128; j += 256) {
            int pos = j >> 7;          // 0..8
            int ci  = j & 127;
            int kh = pos / 3, kw = pos - kh * 3;
            float v = 0.f;
#pragma unroll
            for (int s = 0; s < 8; ++s)
                v += c[s] * dict[((di[s] * CIN + ci) * 3 + kh) * 3 + kw];
            int tile = pos * 4 + (ci >> 5);
            int kpos = (ci >> 3) & 3, kin = ci & 7;
            wpack[tile * 8192 + wid * 2048 + mf * 512 + (kpos * 16 + fl) * 8 + kin]
                = f2bf(v);
        }
        return;
    }

    // ---- pack_x: NCHW fp32 -> zero-padded [ch][iw][kin] bf16 ----
    int idx = blockIdx.x - COUT;
    int ih = idx % HP;         // 0..57
    int b  = idx / HP;         // 0..31
    size_t obase = ((size_t)(b * HP + ih)) * WP * CIN;
    bf16x8* outv = (bf16x8*)(xp + obase);   // 1024 vectors: index = ch*64 + iw

    if (ih == 0 || ih == HP - 1) {
        bf16x8 z = {0, 0, 0, 0, 0, 0, 0, 0};
        for (int e = tid; e < WP * CIN / 8; e += 256) outv[e] = z;
        return;
    }

    __shared__ float xs[CIN][WW + 1];   // +1 pad: odd stride
    int h = ih - 1;
    for (int e = tid; e < CIN * WW; e += 256) {
        int ci = e / WW, w = e - ci * WW;
        xs[ci][w] = x[(((size_t)b * CIN + ci) * HH + h) * WW + w];
    }
    __syncthreads();
    for (int e = tid; e < WP * CIN / 8; e += 256) {
        int iw = e & 63;             // fast-varying -> coalesced stores
        int cb = (e >> 6) << 3;      // ci base
        bf16x8 v = {0, 0, 0, 0, 0, 0, 0, 0};
        if (iw >= 1 && iw <= WW) {
#pragma unroll
            for (int j = 0; j < 8; ++j)
                v[j] = (short)f2bf(xs[cb + j][iw - 1]);
        }
        outv[e] = v;
    }
}

// ---------------------------------------------------------------------------
// Main: implicit-GEMM conv, RESIDENT-B / ZERO-K-LOOP-BARRIER structure.
// R14 (R8-R13 post-mortems: every isolated scheduling fix was null; the
// K-loop's stage+sync structure itself is the plateau):
//  - Block = 256 threads = 4 waves = 256 Cout x ONE output row oh.
//    The ENTIRE K-reduction (36 steps) for row oh needs only input rows
//    oh..oh+2 = 48 KB -> stage once, ONE __syncthreads, then 36 steps with
//    no barriers, no restaging, no vm/lgkm drains. Waves run independent.
//  - B slab LDS [row(3)][ch(16)][iw(64)][kin(8)] = 49.4 KB (+pad);
//    3 blocks/CU by LDS. (256,3) = safe R9 reg envelope (~134 unified,
//    no force-cap cliff: R3/R5 lesson).
//  - B-frag reads: one per-lane vaddr (+cib term), all else 16-bit DS imm
//    (max 45.9 KB < 64 KB); 16B-stride across lanes = conflict-free
//    (0 LDS conflicts all rounds).
//  - A: direct global->reg from L2-hot wpack, coalesced layout (R13),
//    dist-1 afc/afn pipeline.
// ---------------------------------------------------------------------------
__global__ __launch_bounds__(256, 3) void conv_mfma(
    const unsigned short* __restrict__ xp,
    const unsigned short* __restrict__ wpack,
    float* __restrict__ out) {
    // slab: elem = ((row*16 + ch)*64 + iw)*8 + kin; +128 pad for junk-col reads
    __shared__ unsigned short Bl[3 * 16 * 64 * 8 + 128];

    int tid  = threadIdx.x;
    int lane = tid & 63;
    int wid  = tid >> 6;       // 0..3 = Cout slice of 64

    // XCD-bijective swizzle: 1792 = 8 * 224; each XCD gets 4 consecutive b's
    int flat = blockIdx.x;
    int swz  = (flat & 7) * 224 + (flat >> 3);
    int b    = swz / 56;       // 0..31
    int oh   = swz % 56;       // output row

    const int klane = lane >> 4;   // k-group (0..3)
    const int fl    = lane & 15;

    f32x4 acc[4][4];
    f32x4 zero = {0.f, 0.f, 0.f, 0.f};
#pragma unroll
    for (int i = 0; i < 4; ++i)
#pragma unroll
        for (int j = 0; j < 4; ++j) acc[i][j] = zero;

    // A-fragment base (coalesced): af(tile,mf) = ap0 + tile*8192 + mf*512 elems
    const unsigned short* ap0 = wpack + (size_t)wid * 2048 + lane * 8;

    // ---- prologue: stage 3-row slab (48 slices of 1 KB, linear copy) ----
    const unsigned short* xrow = xp + ((size_t)(b * HP + oh)) * 8192;
#pragma unroll
    for (int j = 0; j < 12; ++j) {
        int s = wid + j * 4;           // 0..47 = row*16 + ch
        gload16(xrow + (size_t)(s >> 4) * 8192 + (s & 15) * 512 + lane * 8,
                &Bl[s * 512]);
    }

    bf16x8 afc[4], afn[4];
#pragma unroll
    for (int mf = 0; mf < 4; ++mf)
        afc[mf] = *(const bf16x8*)(ap0 + mf * 512);
    __syncthreads();   // slab resident; ONLY barrier in the kernel

    const unsigned short* apc = ap0;                       // += 8192/cib
    const unsigned short* bl0 = &Bl[klane * 512 + fl * 8]; // += 2048/cib

#pragma unroll 1
    for (int cib = 0; cib < 4; ++cib) {
        const unsigned short* bcur = bl0 + cib * 2048;

#pragma unroll
        for (int pos = 0; pos < 9; ++pos) {
            const int kh = pos / 3, kw = pos - kh * 3;

            // ---- prefetch A(next step) into afn (dist-1 reg pipeline) ----
            if (pos < 8) {
#pragma unroll
                for (int mf = 0; mf < 4; ++mf)
                    afn[mf] = *(const bf16x8*)(apc + (pos + 1) * 32768 + mf * 512);
            } else if (cib < 3) {
#pragma unroll
                for (int mf = 0; mf < 4; ++mf)
                    afn[mf] = *(const bf16x8*)(apc + 8192 + mf * 512);
            }

            // ---- B fragments from resident slab (imm-offset ds_read) ----
            bf16x8 bfr[4];
#pragma unroll
            for (int nf = 0; nf < 4; ++nf)
                bfr[nf] = *(const bf16x8*)(bcur + kh * 8192 + (nf * 16 + kw) * 8);

            // ---- 16 MFMA on afc (loaded a full step ago) ----
            __builtin_amdgcn_s_setprio(1);
#pragma unroll
            for (int mf = 0; mf < 4; ++mf)
#pragma unroll
                for (int nf = 0; nf < 4; ++nf)
                    acc[mf][nf] = __builtin_amdgcn_mfma_f32_16x16x32_bf16(
                        afc[mf], bfr[nf], acc[mf][nf], 0, 0, 0);
            __builtin_amdgcn_s_setprio(0);

            // rotate the register pipeline
#pragma unroll
            for (int mf = 0; mf < 4; ++mf) afc[mf] = afn[mf];
        }
        apc += 8192;
    }

    // Epilogue: C/D layout col = lane&15, row = (lane>>4)*4 + reg (m89-verified)
#pragma unroll
    for (int nf = 0; nf < 4; ++nf) {
        int ow = nf * 16 + fl;
        if (ow < WW) {
#pragma unroll
            for (int mf = 0; mf < 4; ++mf) {
                int ob = wid * 64 + mf * 16 + (lane >> 4) * 4;
                float* dst = out + (((size_t)b * COUT + ob) * HH + oh) * WW + ow;
#pragma unroll
                for (int r = 0; r < 4; ++r)
                    dst[(size_t)r * HH * WW] = acc[mf][nf][r];
            }
        }
    }
}

extern "C" void kernel_launch(void* const* d_in, const int* in_sizes, int n_in,
                              void* d_out, int out_size, void* d_ws, size_t ws_size,
                              hipStream_t stream) {
    const float* x    = (const float*)d_in[0];
    const float* dict = (const float*)d_in[1];
    const float* coef = (const float*)d_in[2];
    const int*   idxw = (const int*)d_in[3];
    float* out = (float*)d_out;

    unsigned short* xp    = (unsigned short*)d_ws;
    unsigned short* wpack = xp + XP_ELEMS;

    prep<<<dim3(COUT + HP * NB), dim3(256), 0, stream>>>(x, dict, coef, idxw, wpack, xp);
    conv_mfma<<<dim3(NB * 56), dim3(256), 0, stream>>>(xp, wpack, out);
}